// Round 7
// baseline (83.742 us; speedup 1.0000x reference)
//
#include <hip/hip_runtime.h>
#include <math.h>
#include <stdint.h>

#define N_FEAT 8192
#define DIM 512
#define KC 64
#define MF 128
#define TFT 32
#define NBLK 320       // grid: >= max tiles (320) and >= phase-A units (320)
#define BKC 64         // d-chunk
#define NCH (DIM / BKC)
#define BFLAG (1 << 20)
#define BMASK (BFLAG - 1)
#define MAGIC1 0x13579BDF
#define MAGIC2 0x2468ACE1

typedef __attribute__((ext_vector_type(8))) _Float16 f16x8;
typedef __attribute__((ext_vector_type(4))) float f32x4;
typedef unsigned short ush;

__device__ __forceinline__ float wave_reduce_sum(float s) {
#pragma unroll
  for (int o = 32; o; o >>= 1) s += __shfl_xor(s, o);
  return s;
}

__device__ __forceinline__ uint4 cvt8(float4 a, float4 b, float& sq) {
  sq = fmaf(a.x, a.x, sq); sq = fmaf(a.y, a.y, sq);
  sq = fmaf(a.z, a.z, sq); sq = fmaf(a.w, a.w, sq);
  sq = fmaf(b.x, b.x, sq); sq = fmaf(b.y, b.y, sq);
  sq = fmaf(b.z, b.z, sq); sq = fmaf(b.w, b.w, sq);
  union { _Float16 h[8]; uint4 v; } o;
  o.h[0] = (_Float16)a.x; o.h[1] = (_Float16)a.y;
  o.h[2] = (_Float16)a.z; o.h[3] = (_Float16)a.w;
  o.h[4] = (_Float16)b.x; o.h[5] = (_Float16)b.y;
  o.h[6] = (_Float16)b.z; o.h[7] = (_Float16)b.w;
  return o.v;
}

#define ALOAD(p) __hip_atomic_load((p), __ATOMIC_RELAXED, __HIP_MEMORY_SCOPE_AGENT)
#define ASTORE(p, v) __hip_atomic_store((p), (v), __ATOMIC_RELAXED, __HIP_MEMORY_SCOPE_AGENT)
#define AADD(p, v) __hip_atomic_fetch_add((p), (v), __ATOMIC_RELAXED, __HIP_MEMORY_SCOPE_AGENT)
#define AOR(p, v) __hip_atomic_fetch_or((p), (v), __ATOMIC_RELAXED, __HIP_MEMORY_SCOPE_AGENT)

// Single fused kernel. Phase A: blocks 0..127 coarse-assign (fp16 MFMA, fused
// f32->fp16 feature conversion + exact f2/c2 norms); blocks 128..319 convert
// fine prototypes + p2 norms. Device-wide barrier. Phase B: 320 self-scheduled
// fine 32f x 128m MFMA tiles -> per-feature min -> mean.
__global__ void __launch_bounds__(256, 2) fused_all_kernel(
    const float* __restrict__ feat, const float* __restrict__ coarse,
    const float* __restrict__ fine, ush* __restrict__ feat_h,
    ush* __restrict__ fine_h, float* __restrict__ f2, float* __restrict__ p2,
    int* __restrict__ assign, int* __restrict__ bar, float* __restrict__ out) {
  union SMem {
    struct { ush Ah[2][64 * 64]; ush Bh[2][64 * 64]; float c2s[64]; } a;
    struct {
      ush Ab[2][32 * 64]; ush Bb[2][128 * 64]; float red[32][5];
      int hist[64]; int meta[3]; int wsum[4]; int glist[32];
    } b;
  };
  __shared__ SMem sm;

  int t = threadIdx.x, bid = blockIdx.x;
  int l = t & 63, w = t >> 6;

  // ---- init gate: make barrier state {C=0} regardless of ws poison ----
  if (t == 0) {
    if (bid == 0) {
      bool ok = (ALOAD(bar + 1) == (int)MAGIC1) && (ALOAD(bar + 2) == (int)MAGIC2);
      if (!ok) {
        ASTORE(bar, 0);
        __threadfence();
        ASTORE(bar + 1, (int)MAGIC1);
        ASTORE(bar + 2, (int)MAGIC2);
      }
    } else {
      while (ALOAD(bar + 1) != (int)MAGIC1 || ALOAD(bar + 2) != (int)MAGIC2)
        __builtin_amdgcn_s_sleep(2);
      __threadfence();
    }
  }
  __syncthreads();

  if (bid == 0 && t == 0) out[0] = 0.f;

  // =================== PHASE A ===================
  if (bid < 128) {
    // ---- coarse assignment, 64 features x 64 clusters, fp16 MFMA ----
    int n0 = bid * 64;
    int slot = t & 7, r0 = t >> 3;
    int xs = (slot ^ (r0 & 7)) * 8;
    const float* a0 = feat + (size_t)(n0 + r0) * DIM + slot * 8;
    const float* a1 = a0 + (size_t)32 * DIM;
    const float* b0 = coarse + (size_t)r0 * DIM + slot * 8;
    const float* b1 = b0 + (size_t)32 * DIM;
    ush* fh0 = feat_h + (size_t)(n0 + r0) * DIM + slot * 8;
    ush* fh1 = fh0 + (size_t)32 * DIM;
    int offA0 = r0 * 64 + xs, offA1 = (r0 + 32) * 64 + xs;

    int lc = l & 15, lk = l >> 4;
    int sx0 = (lk ^ (l & 7)) * 8;
    int eA = (w * 16 + lc) * 64;
    int eB0 = lc * 64, eB1 = (16 + lc) * 64, eB2 = (32 + lc) * 64, eB3 = (48 + lc) * 64;

    float sa0 = 0.f, sa1 = 0.f, sb0 = 0.f, sb1 = 0.f;
    f32x4 acc0 = {0.f, 0.f, 0.f, 0.f}, acc1 = acc0, acc2 = acc0, acc3 = acc0;

    float4 va0a = *(const float4*)a0, va0b = *(const float4*)(a0 + 4);
    float4 va1a = *(const float4*)a1, va1b = *(const float4*)(a1 + 4);
    float4 vb0a = *(const float4*)b0, vb0b = *(const float4*)(b0 + 4);
    float4 vb1a = *(const float4*)b1, vb1b = *(const float4*)(b1 + 4);
    {
      uint4 hA0 = cvt8(va0a, va0b, sa0);
      uint4 hA1 = cvt8(va1a, va1b, sa1);
      uint4 hB0 = cvt8(vb0a, vb0b, sb0);
      uint4 hB1 = cvt8(vb1a, vb1b, sb1);
      *(uint4*)&sm.a.Ah[0][offA0] = hA0; *(uint4*)&sm.a.Ah[0][offA1] = hA1;
      *(uint4*)&sm.a.Bh[0][offA0] = hB0; *(uint4*)&sm.a.Bh[0][offA1] = hB1;
      *(uint4*)fh0 = hA0; *(uint4*)fh1 = hA1;
    }
    __syncthreads();

    for (int c = 0; c < NCH; c++) {
      int cur = c & 1;
      if (c + 1 < NCH) {
        int go = (c + 1) * BKC;
        va0a = *(const float4*)(a0 + go); va0b = *(const float4*)(a0 + go + 4);
        va1a = *(const float4*)(a1 + go); va1b = *(const float4*)(a1 + go + 4);
        vb0a = *(const float4*)(b0 + go); vb0b = *(const float4*)(b0 + go + 4);
        vb1a = *(const float4*)(b1 + go); vb1b = *(const float4*)(b1 + go + 4);
      }
#pragma unroll
      for (int ksub = 0; ksub < 2; ksub++) {
        int sx = sx0 ^ (ksub * 32);
        f16x8 av = *(const f16x8*)&sm.a.Ah[cur][eA + sx];
        acc0 = __builtin_amdgcn_mfma_f32_16x16x32_f16(av, *(const f16x8*)&sm.a.Bh[cur][eB0 + sx], acc0, 0, 0, 0);
        acc1 = __builtin_amdgcn_mfma_f32_16x16x32_f16(av, *(const f16x8*)&sm.a.Bh[cur][eB1 + sx], acc1, 0, 0, 0);
        acc2 = __builtin_amdgcn_mfma_f32_16x16x32_f16(av, *(const f16x8*)&sm.a.Bh[cur][eB2 + sx], acc2, 0, 0, 0);
        acc3 = __builtin_amdgcn_mfma_f32_16x16x32_f16(av, *(const f16x8*)&sm.a.Bh[cur][eB3 + sx], acc3, 0, 0, 0);
      }
      if (c + 1 < NCH) {
        int go = (c + 1) * BKC;
        int nb = cur ^ 1;
        uint4 hA0 = cvt8(va0a, va0b, sa0);
        uint4 hA1 = cvt8(va1a, va1b, sa1);
        uint4 hB0 = cvt8(vb0a, vb0b, sb0);
        uint4 hB1 = cvt8(vb1a, vb1b, sb1);
        *(uint4*)&sm.a.Ah[nb][offA0] = hA0; *(uint4*)&sm.a.Ah[nb][offA1] = hA1;
        *(uint4*)&sm.a.Bh[nb][offA0] = hB0; *(uint4*)&sm.a.Bh[nb][offA1] = hB1;
        *(uint4*)(fh0 + go) = hA0; *(uint4*)(fh1 + go) = hA1;
      }
      __syncthreads();
    }

#pragma unroll
    for (int m = 1; m < 8; m <<= 1) {
      sa0 += __shfl_xor(sa0, m); sa1 += __shfl_xor(sa1, m);
      sb0 += __shfl_xor(sb0, m); sb1 += __shfl_xor(sb1, m);
    }
    if (slot == 0) {
      f2[n0 + r0] = sa0; f2[n0 + r0 + 32] = sa1;
      sm.a.c2s[r0] = sb0; sm.a.c2s[r0 + 32] = sb1;
    }
    __syncthreads();

    float c2v0 = sm.a.c2s[lc], c2v1 = sm.a.c2s[16 + lc];
    float c2v2 = sm.a.c2s[32 + lc], c2v3 = sm.a.c2s[48 + lc];
#pragma unroll
    for (int j = 0; j < 4; j++) {
      float bv = c2v0 - 2.f * acc0[j];
      int bi = lc;
      float v1 = c2v1 - 2.f * acc1[j];
      if (v1 < bv) { bv = v1; bi = 16 + lc; }
      float v2 = c2v2 - 2.f * acc2[j];
      if (v2 < bv) { bv = v2; bi = 32 + lc; }
      float v3 = c2v3 - 2.f * acc3[j];
      if (v3 < bv) { bv = v3; bi = 48 + lc; }
#pragma unroll
      for (int mask = 1; mask < 16; mask <<= 1) {
        float ov = __shfl_xor(bv, mask);
        int oi = __shfl_xor(bi, mask);
        if (ov < bv || (ov == bv && oi < bi)) { bv = ov; bi = oi; }
      }
      if (lc == 0) assign[n0 + w * 16 + lk * 4 + j] = bi;
    }
  } else {
    // ---- converter blocks: fine -> fp16 + p2 norms (192 blocks, strided) ----
    for (int g = bid - 128; g < 2048; g += 192) {
      int r = g * 4 + w;
      const float* src = fine + (size_t)r * DIM + l * 8;
      float4 a = *(const float4*)src;
      float4 b = *(const float4*)(src + 4);
      float s = 0.f;
      uint4 h = cvt8(a, b, s);
      *(uint4*)(fine_h + (size_t)r * DIM + l * 8) = h;
      s = wave_reduce_sum(s);
      if (l == 0) p2[r] = s;
    }
  }

  // =================== DEVICE-WIDE BARRIER ===================
  if (t == 0) {
    __threadfence();                                  // release phase-A writes
    int old = AADD(bar, 1);
    if ((old & BMASK) == NBLK - 1) AOR(bar, BFLAG);   // last arriver sets flag
    while (!(ALOAD(bar) & BFLAG)) __builtin_amdgcn_s_sleep(2);
    int ret = AADD(bar, -1) - 1;
    if ((ret & BMASK) == 0) ASTORE(bar, 0);           // last leaver resets C=0
    __threadfence();                                  // acquire
  }
  __syncthreads();

  // =================== PHASE B: fine tiles ===================
  if (t < 64) sm.b.hist[t] = 0;
  __syncthreads();
#pragma unroll
  for (int j = 0; j < 32; j++) {
    int a = assign[t + j * 256];
    atomicAdd(&sm.b.hist[a], 1);
  }
  __syncthreads();
  if (t < 64) {
    int c = sm.b.hist[t];
    int nt = (c + TFT - 1) / TFT;
    int s2 = nt;
#pragma unroll
    for (int o = 1; o < 64; o <<= 1) {
      int v = __shfl_up(s2, o);
      if (t >= o) s2 += v;
    }
    int tb = s2 - nt;
    if (t == 63) sm.b.meta[2] = s2;
    if (bid >= tb && bid < tb + nt) { sm.b.meta[0] = t; sm.b.meta[1] = bid - tb; }
  }
  __syncthreads();
  if (bid >= sm.b.meta[2]) return;
  int k = sm.b.meta[0], tile = sm.b.meta[1];
  int nk = sm.b.hist[k];
  int f0 = tile * TFT;
  int nf = min(TFT, nk - f0);

  int cntk = 0;
#pragma unroll
  for (int j = 0; j < 32; j++) cntk += (assign[t + j * 256] == k) ? 1 : 0;
  int inc = cntk;
#pragma unroll
  for (int o = 1; o < 64; o <<= 1) {
    int v = __shfl_up(inc, o);
    if (l >= o) inc += v;
  }
  if (l == 63) sm.b.wsum[w] = inc;
  __syncthreads();
  int rank = inc - cntk;
#pragma unroll
  for (int w2 = 0; w2 < 4; w2++) rank += (w2 < w) ? sm.b.wsum[w2] : 0;
#pragma unroll
  for (int j = 0; j < 32; j++) {
    int i = t + j * 256;
    if (assign[i] == k) {
      int rr = rank - f0;
      if (rr >= 0 && rr < TFT) sm.b.glist[rr] = i;
      rank++;
    }
  }
  __syncthreads();

  int sl8 = l >> 3, sl7 = l & 7;
  int slotw = sl7 ^ sl8;

  int arow = w * 8 + sl8;
  int agidx = sm.b.glist[min(arow, nf - 1)];
  const ush* asrc = feat_h + (size_t)agidx * DIM + sl7 * 8;
  int aoff = arow * 64 + slotw * 8;
  int brow0 = w * 32 + 0 * 8 + sl8;
  int brow1 = w * 32 + 1 * 8 + sl8;
  int brow2 = w * 32 + 2 * 8 + sl8;
  int brow3 = w * 32 + 3 * 8 + sl8;
  const ush* bsrc0 = fine_h + ((size_t)k * MF + brow0) * DIM + sl7 * 8;
  const ush* bsrc1 = fine_h + ((size_t)k * MF + brow1) * DIM + sl7 * 8;
  const ush* bsrc2 = fine_h + ((size_t)k * MF + brow2) * DIM + sl7 * 8;
  const ush* bsrc3 = fine_h + ((size_t)k * MF + brow3) * DIM + sl7 * 8;
  int boff0 = brow0 * 64 + slotw * 8;
  int boff1 = brow1 * 64 + slotw * 8;
  int boff2 = brow2 * 64 + slotw * 8;
  int boff3 = brow3 * 64 + slotw * 8;

  int lc = l & 15, lk = l >> 4;
  int sx0 = (lk ^ sl7) * 8;
  int eA0 = lc * 64, eA1 = (16 + lc) * 64;
  int eB0 = (w * 32 + lc) * 64, eB1 = (w * 32 + 16 + lc) * 64;

  float p2v0 = p2[k * MF + w * 32 + lc];
  float p2v1 = p2[k * MF + w * 32 + 16 + lc];

  f32x4 acc00 = {0.f, 0.f, 0.f, 0.f}, acc01 = acc00, acc10 = acc00, acc11 = acc00;

  uint4 sA = *(const uint4*)asrc;
  uint4 sB0 = *(const uint4*)bsrc0;
  uint4 sB1 = *(const uint4*)bsrc1;
  uint4 sB2 = *(const uint4*)bsrc2;
  uint4 sB3 = *(const uint4*)bsrc3;
  *(uint4*)&sm.b.Ab[0][aoff] = sA;
  *(uint4*)&sm.b.Bb[0][boff0] = sB0;
  *(uint4*)&sm.b.Bb[0][boff1] = sB1;
  *(uint4*)&sm.b.Bb[0][boff2] = sB2;
  *(uint4*)&sm.b.Bb[0][boff3] = sB3;
  __syncthreads();

  for (int c = 0; c < NCH; c++) {
    int cur = c & 1;
    if (c + 1 < NCH) {
      int go = (c + 1) * BKC;
      sA = *(const uint4*)(asrc + go);
      sB0 = *(const uint4*)(bsrc0 + go);
      sB1 = *(const uint4*)(bsrc1 + go);
      sB2 = *(const uint4*)(bsrc2 + go);
      sB3 = *(const uint4*)(bsrc3 + go);
    }
#pragma unroll
    for (int ksub = 0; ksub < 2; ksub++) {
      int sx = sx0 ^ (ksub * 32);
      f16x8 a0 = *(const f16x8*)&sm.b.Ab[cur][eA0 + sx];
      f16x8 a1 = *(const f16x8*)&sm.b.Ab[cur][eA1 + sx];
      f16x8 b0 = *(const f16x8*)&sm.b.Bb[cur][eB0 + sx];
      f16x8 b1 = *(const f16x8*)&sm.b.Bb[cur][eB1 + sx];
      acc00 = __builtin_amdgcn_mfma_f32_16x16x32_f16(a0, b0, acc00, 0, 0, 0);
      acc01 = __builtin_amdgcn_mfma_f32_16x16x32_f16(a0, b1, acc01, 0, 0, 0);
      acc10 = __builtin_amdgcn_mfma_f32_16x16x32_f16(a1, b0, acc10, 0, 0, 0);
      acc11 = __builtin_amdgcn_mfma_f32_16x16x32_f16(a1, b1, acc11, 0, 0, 0);
    }
    if (c + 1 < NCH) {
      int nb = cur ^ 1;
      *(uint4*)&sm.b.Ab[nb][aoff] = sA;
      *(uint4*)&sm.b.Bb[nb][boff0] = sB0;
      *(uint4*)&sm.b.Bb[nb][boff1] = sB1;
      *(uint4*)&sm.b.Bb[nb][boff2] = sB2;
      *(uint4*)&sm.b.Bb[nb][boff3] = sB3;
    }
    __syncthreads();
  }

  float v0[4], v1[4];
#pragma unroll
  for (int j = 0; j < 4; j++) {
    v0[j] = fminf(p2v0 - 2.f * acc00[j], p2v1 - 2.f * acc01[j]);
    v1[j] = fminf(p2v0 - 2.f * acc10[j], p2v1 - 2.f * acc11[j]);
  }
#pragma unroll
  for (int mask = 1; mask < 16; mask <<= 1) {
#pragma unroll
    for (int j = 0; j < 4; j++) {
      v0[j] = fminf(v0[j], __shfl_xor(v0[j], mask));
      v1[j] = fminf(v1[j], __shfl_xor(v1[j], mask));
    }
  }
  if (lc == 0) {
#pragma unroll
    for (int j = 0; j < 4; j++) {
      sm.b.red[lk * 4 + j][w] = v0[j];
      sm.b.red[16 + lk * 4 + j][w] = v1[j];
    }
  }
  __syncthreads();
  if (t < 64) {
    float val = 0.f;
    if (t < nf) {
      float m = fminf(fminf(sm.b.red[t][0], sm.b.red[t][1]),
                      fminf(sm.b.red[t][2], sm.b.red[t][3]));
      float d2 = f2[sm.b.glist[t]] + m;
      val = sqrtf(fmaxf(d2, 0.f)) * (1.0f / (float)N_FEAT);
    }
    val = wave_reduce_sum(val);
    if (t == 0) atomicAdd(out, val);
  }
}

extern "C" void kernel_launch(void* const* d_in, const int* in_sizes, int n_in,
                              void* d_out, int out_size, void* d_ws, size_t ws_size,
                              hipStream_t stream) {
  (void)in_sizes; (void)n_in; (void)out_size; (void)ws_size;
  const float* feat   = (const float*)d_in[0];
  const float* coarse = (const float*)d_in[1];
  const float* fine   = (const float*)d_in[2];
  float* out = (float*)d_out;

  ush* feat_h = (ush*)d_ws;                          // 8192*512
  ush* fine_h = feat_h + (size_t)N_FEAT * DIM;       // 8192*512
  float* f2   = (float*)(fine_h + (size_t)KC * MF * DIM);  // 8192
  float* p2   = f2 + N_FEAT;                // 8192
  int* assign = (int*)(p2 + KC * MF);       // 8192
  int* bar    = assign + N_FEAT;            // 3 (barrier counter + 2 magics)

  fused_all_kernel<<<NBLK, 256, 0, stream>>>(
      feat, coarse, fine, feat_h, fine_h, f2, p2, assign, bar, out);
}

// Round 8
// 33.958 us; speedup vs baseline: 2.4661x; 2.4661x over previous
//
#include <hip/hip_runtime.h>
#include <math.h>
#include <stdint.h>

#define N_FEAT 8192
#define DIM 512
#define KC 64
#define MF 128
#define TFT 32
#define MAXTILES 320   // max sum ceil(nk/32), sum nk = 8192
#define BKC 64         // d-chunk
#define NCH (DIM / BKC)

typedef __attribute__((ext_vector_type(8))) _Float16 f16x8;
typedef __attribute__((ext_vector_type(4))) float f32x4;
typedef unsigned short ush;

__device__ __forceinline__ float wave_reduce_sum(float s) {
#pragma unroll
  for (int o = 32; o; o >>= 1) s += __shfl_xor(s, o);
  return s;
}

// convert 8 f32 -> 8 fp16 packed in uint4; accumulate exact f32 sq-sum
__device__ __forceinline__ uint4 cvt8(float4 a, float4 b, float& sq) {
  sq = fmaf(a.x, a.x, sq); sq = fmaf(a.y, a.y, sq);
  sq = fmaf(a.z, a.z, sq); sq = fmaf(a.w, a.w, sq);
  sq = fmaf(b.x, b.x, sq); sq = fmaf(b.y, b.y, sq);
  sq = fmaf(b.z, b.z, sq); sq = fmaf(b.w, b.w, sq);
  union { _Float16 h[8]; uint4 v; } o;
  o.h[0] = (_Float16)a.x; o.h[1] = (_Float16)a.y;
  o.h[2] = (_Float16)a.z; o.h[3] = (_Float16)a.w;
  o.h[4] = (_Float16)b.x; o.h[5] = (_Float16)b.y;
  o.h[6] = (_Float16)b.z; o.h[7] = (_Float16)b.w;
  return o.v;
}

__device__ __forceinline__ uint4 cvt8n(float4 a, float4 b) {
  union { _Float16 h[8]; uint4 v; } o;
  o.h[0] = (_Float16)a.x; o.h[1] = (_Float16)a.y;
  o.h[2] = (_Float16)a.z; o.h[3] = (_Float16)a.w;
  o.h[4] = (_Float16)b.x; o.h[5] = (_Float16)b.y;
  o.h[6] = (_Float16)b.z; o.h[7] = (_Float16)b.w;
  return o.v;
}

// K1: blocks 0..127 = coarse assignment (fp16 MFMA from in-register cvt of f32,
// exact f2/c2 norms, per-block histogram -> hist_part); blocks 128..383 =
// fine -> fp16 conversion + p2 norms.
__global__ void __launch_bounds__(256) k1_assign_cvt_kernel(
    const float* __restrict__ feat, const float* __restrict__ coarse,
    const float* __restrict__ fine, ush* __restrict__ fine_h,
    float* __restrict__ f2, float* __restrict__ p2, int* __restrict__ assign,
    int* __restrict__ hist_part, float* __restrict__ out) {
  __shared__ ush Ah[2][64 * 64];
  __shared__ ush Bh[2][64 * 64];
  __shared__ float c2s[64];
  __shared__ int histL[64];

  int t = threadIdx.x, bid = blockIdx.x;
  int l = t & 63, w = t >> 6;

  if (bid >= 128) {   // ---- converters: fine -> fp16 + p2 (32 rows/block)
    int base = (bid - 128) * 32;
#pragma unroll 2
    for (int i = 0; i < 8; i++) {
      int r = base + i * 4 + w;
      const float* src = fine + (size_t)r * DIM + l * 8;
      float4 a = *(const float4*)src;
      float4 b = *(const float4*)(src + 4);
      float s = 0.f;
      uint4 h = cvt8(a, b, s);
      *(uint4*)(fine_h + (size_t)r * DIM + l * 8) = h;
      s = wave_reduce_sum(s);
      if (l == 0) p2[r] = s;
    }
    return;
  }

  if (bid == 0 && t == 0) out[0] = 0.f;
  if (t < 64) histL[t] = 0;

  int n0 = bid * 64;
  int slot = t & 7, r0 = t >> 3;
  int xs = (slot ^ (r0 & 7)) * 8;          // XOR 16B-slot swizzle
  const float* a0 = feat + (size_t)(n0 + r0) * DIM + slot * 8;
  const float* a1 = a0 + (size_t)32 * DIM;
  const float* b0 = coarse + (size_t)r0 * DIM + slot * 8;
  const float* b1 = b0 + (size_t)32 * DIM;
  int offA0 = r0 * 64 + xs, offA1 = (r0 + 32) * 64 + xs;

  int lc = l & 15, lk = l >> 4;
  int sx0 = (lk ^ (l & 7)) * 8;
  int eA = (w * 16 + lc) * 64;
  int eB0 = lc * 64, eB1 = (16 + lc) * 64, eB2 = (32 + lc) * 64, eB3 = (48 + lc) * 64;

  float sa0 = 0.f, sa1 = 0.f, sb0 = 0.f, sb1 = 0.f;
  f32x4 acc0 = {0.f, 0.f, 0.f, 0.f}, acc1 = acc0, acc2 = acc0, acc3 = acc0;

  float4 va0a = *(const float4*)a0, va0b = *(const float4*)(a0 + 4);
  float4 va1a = *(const float4*)a1, va1b = *(const float4*)(a1 + 4);
  float4 vb0a = *(const float4*)b0, vb0b = *(const float4*)(b0 + 4);
  float4 vb1a = *(const float4*)b1, vb1b = *(const float4*)(b1 + 4);
  {
    uint4 hA0 = cvt8(va0a, va0b, sa0);
    uint4 hA1 = cvt8(va1a, va1b, sa1);
    uint4 hB0 = cvt8(vb0a, vb0b, sb0);
    uint4 hB1 = cvt8(vb1a, vb1b, sb1);
    *(uint4*)&Ah[0][offA0] = hA0; *(uint4*)&Ah[0][offA1] = hA1;
    *(uint4*)&Bh[0][offA0] = hB0; *(uint4*)&Bh[0][offA1] = hB1;
  }
  __syncthreads();

  for (int c = 0; c < NCH; c++) {
    int cur = c & 1;
    if (c + 1 < NCH) {                     // issue next-chunk loads early
      int go = (c + 1) * BKC;
      va0a = *(const float4*)(a0 + go); va0b = *(const float4*)(a0 + go + 4);
      va1a = *(const float4*)(a1 + go); va1b = *(const float4*)(a1 + go + 4);
      vb0a = *(const float4*)(b0 + go); vb0b = *(const float4*)(b0 + go + 4);
      vb1a = *(const float4*)(b1 + go); vb1b = *(const float4*)(b1 + go + 4);
    }
#pragma unroll
    for (int ksub = 0; ksub < 2; ksub++) {
      int sx = sx0 ^ (ksub * 32);
      f16x8 av = *(const f16x8*)&Ah[cur][eA + sx];
      acc0 = __builtin_amdgcn_mfma_f32_16x16x32_f16(av, *(const f16x8*)&Bh[cur][eB0 + sx], acc0, 0, 0, 0);
      acc1 = __builtin_amdgcn_mfma_f32_16x16x32_f16(av, *(const f16x8*)&Bh[cur][eB1 + sx], acc1, 0, 0, 0);
      acc2 = __builtin_amdgcn_mfma_f32_16x16x32_f16(av, *(const f16x8*)&Bh[cur][eB2 + sx], acc2, 0, 0, 0);
      acc3 = __builtin_amdgcn_mfma_f32_16x16x32_f16(av, *(const f16x8*)&Bh[cur][eB3 + sx], acc3, 0, 0, 0);
    }
    if (c + 1 < NCH) {                     // convert + write after MFMA
      int nb = cur ^ 1;
      uint4 hA0 = cvt8(va0a, va0b, sa0);
      uint4 hA1 = cvt8(va1a, va1b, sa1);
      uint4 hB0 = cvt8(vb0a, vb0b, sb0);
      uint4 hB1 = cvt8(vb1a, vb1b, sb1);
      *(uint4*)&Ah[nb][offA0] = hA0; *(uint4*)&Ah[nb][offA1] = hA1;
      *(uint4*)&Bh[nb][offA0] = hB0; *(uint4*)&Bh[nb][offA1] = hB1;
    }
    __syncthreads();
  }

  // exact f32 row norms (reduce across the 8 slot-lanes of each staging row)
#pragma unroll
  for (int m = 1; m < 8; m <<= 1) {
    sa0 += __shfl_xor(sa0, m); sa1 += __shfl_xor(sa1, m);
    sb0 += __shfl_xor(sb0, m); sb1 += __shfl_xor(sb1, m);
  }
  if (slot == 0) {
    f2[n0 + r0] = sa0; f2[n0 + r0 + 32] = sa1;
    c2s[r0] = sb0;     c2s[r0 + 32] = sb1;
  }
  __syncthreads();

  // argmin_k (c2[k] - 2 f.c), first-min tiebreak; store assign + local hist
  float c2v0 = c2s[lc], c2v1 = c2s[16 + lc], c2v2 = c2s[32 + lc], c2v3 = c2s[48 + lc];
#pragma unroll
  for (int j = 0; j < 4; j++) {
    float bv = c2v0 - 2.f * acc0[j];
    int bi = lc;
    float v1 = c2v1 - 2.f * acc1[j];
    if (v1 < bv) { bv = v1; bi = 16 + lc; }
    float v2 = c2v2 - 2.f * acc2[j];
    if (v2 < bv) { bv = v2; bi = 32 + lc; }
    float v3 = c2v3 - 2.f * acc3[j];
    if (v3 < bv) { bv = v3; bi = 48 + lc; }
#pragma unroll
    for (int mask = 1; mask < 16; mask <<= 1) {
      float ov = __shfl_xor(bv, mask);
      int oi = __shfl_xor(bi, mask);
      if (ov < bv || (ov == bv && oi < bi)) { bv = ov; bi = oi; }
    }
    if (lc == 0) {
      assign[n0 + w * 16 + lk * 4 + j] = bi;
      atomicAdd(&histL[bi], 1);
    }
  }
  __syncthreads();
  if (t < 64) hist_part[bid * 64 + t] = histL[t];
}

// K2: fine distances via fp16 MFMA, self-scheduled from hist partials.
// Per block: reduce hist_part -> (k,tile) map -> rank-scan gather list ->
// 32f x 128m MFMA tile (A staged from f32 with on-the-fly cvt) -> min -> out.
__global__ void __launch_bounds__(256) fine_mfma_kernel(
    const float* __restrict__ feat, const ush* __restrict__ fine_h,
    const float* __restrict__ f2, const float* __restrict__ p2,
    const int* __restrict__ assign, const int* __restrict__ hist_part,
    float* __restrict__ out) {
  __shared__ int hpart[4][64];
  __shared__ int hist[64];
  __shared__ int meta[3];
  __shared__ int wsum[4];
  __shared__ int glist[32];
  __shared__ ush Ab[2][32 * 64];
  __shared__ ush Bb[2][128 * 64];
  __shared__ float red[32][5];

  int t = threadIdx.x, bid = blockIdx.x;
  int l = t & 63, w = t >> 6;

  // hist from K1 partials (no LDS-atomic histogram)
  {
    int ksl = t & 63;
    int p0 = w * 32;
    int ps = 0;
#pragma unroll 8
    for (int p = 0; p < 32; p++) ps += hist_part[(p0 + p) * 64 + ksl];
    hpart[w][ksl] = ps;
  }
  __syncthreads();
  if (t < 64) {
    int c = hpart[0][t] + hpart[1][t] + hpart[2][t] + hpart[3][t];
    hist[t] = c;
    int nt = (c + TFT - 1) / TFT;
    int s2 = nt;
#pragma unroll
    for (int o = 1; o < 64; o <<= 1) {
      int v = __shfl_up(s2, o);
      if (t >= o) s2 += v;
    }
    int tb = s2 - nt;
    if (t == 63) meta[2] = s2;
    if (bid >= tb && bid < tb + nt) { meta[0] = t; meta[1] = bid - tb; }
  }
  __syncthreads();
  if (bid >= meta[2]) return;
  int k = meta[0], tile = meta[1];
  int nk = hist[k];
  int f0 = tile * TFT;
  int nf = min(TFT, nk - f0);

  // rank-scan: build this tile's gather list (fixed strided order)
  int cntk = 0;
#pragma unroll
  for (int j = 0; j < 32; j++) cntk += (assign[t + j * 256] == k) ? 1 : 0;
  int inc = cntk;
#pragma unroll
  for (int o = 1; o < 64; o <<= 1) {
    int v = __shfl_up(inc, o);
    if (l >= o) inc += v;
  }
  if (l == 63) wsum[w] = inc;
  __syncthreads();
  int rank = inc - cntk;
#pragma unroll
  for (int w2 = 0; w2 < 4; w2++) rank += (w2 < w) ? wsum[w2] : 0;
#pragma unroll
  for (int j = 0; j < 32; j++) {
    int i = t + j * 256;
    if (assign[i] == k) {
      int rr = rank - f0;
      if (rr >= 0 && rr < TFT) glist[rr] = i;
      rank++;
    }
  }
  __syncthreads();

  int sl8 = l >> 3, sl7 = l & 7;
  int slotw = sl7 ^ sl8;

  int arow = w * 8 + sl8;
  int agidx = glist[min(arow, nf - 1)];
  const float* asrc = feat + (size_t)agidx * DIM + sl7 * 8;   // f32 gather
  int aoff = arow * 64 + slotw * 8;
  int brow0 = w * 32 + 0 * 8 + sl8;
  int brow1 = w * 32 + 1 * 8 + sl8;
  int brow2 = w * 32 + 2 * 8 + sl8;
  int brow3 = w * 32 + 3 * 8 + sl8;
  const ush* bsrc0 = fine_h + ((size_t)k * MF + brow0) * DIM + sl7 * 8;
  const ush* bsrc1 = fine_h + ((size_t)k * MF + brow1) * DIM + sl7 * 8;
  const ush* bsrc2 = fine_h + ((size_t)k * MF + brow2) * DIM + sl7 * 8;
  const ush* bsrc3 = fine_h + ((size_t)k * MF + brow3) * DIM + sl7 * 8;
  int boff0 = brow0 * 64 + slotw * 8;
  int boff1 = brow1 * 64 + slotw * 8;
  int boff2 = brow2 * 64 + slotw * 8;
  int boff3 = brow3 * 64 + slotw * 8;

  int lc = l & 15, lk = l >> 4;
  int sx0 = (lk ^ sl7) * 8;
  int eA0 = lc * 64, eA1 = (16 + lc) * 64;
  int eB0 = (w * 32 + lc) * 64, eB1 = (w * 32 + 16 + lc) * 64;

  float p2v0 = p2[k * MF + w * 32 + lc];
  float p2v1 = p2[k * MF + w * 32 + 16 + lc];

  f32x4 acc00 = {0.f, 0.f, 0.f, 0.f}, acc01 = acc00, acc10 = acc00, acc11 = acc00;

  float4 fAa = *(const float4*)asrc, fAb = *(const float4*)(asrc + 4);
  uint4 sB0 = *(const uint4*)bsrc0;
  uint4 sB1 = *(const uint4*)bsrc1;
  uint4 sB2 = *(const uint4*)bsrc2;
  uint4 sB3 = *(const uint4*)bsrc3;
  *(uint4*)&Ab[0][aoff] = cvt8n(fAa, fAb);
  *(uint4*)&Bb[0][boff0] = sB0;
  *(uint4*)&Bb[0][boff1] = sB1;
  *(uint4*)&Bb[0][boff2] = sB2;
  *(uint4*)&Bb[0][boff3] = sB3;
  __syncthreads();

  for (int c = 0; c < NCH; c++) {
    int cur = c & 1;
    if (c + 1 < NCH) {                     // issue next-chunk loads early
      int go = (c + 1) * BKC;
      fAa = *(const float4*)(asrc + go); fAb = *(const float4*)(asrc + go + 4);
      sB0 = *(const uint4*)(bsrc0 + go);
      sB1 = *(const uint4*)(bsrc1 + go);
      sB2 = *(const uint4*)(bsrc2 + go);
      sB3 = *(const uint4*)(bsrc3 + go);
    }
#pragma unroll
    for (int ksub = 0; ksub < 2; ksub++) {
      int sx = sx0 ^ (ksub * 32);
      f16x8 a0 = *(const f16x8*)&Ab[cur][eA0 + sx];
      f16x8 a1 = *(const f16x8*)&Ab[cur][eA1 + sx];
      f16x8 b0 = *(const f16x8*)&Bb[cur][eB0 + sx];
      f16x8 b1 = *(const f16x8*)&Bb[cur][eB1 + sx];
      acc00 = __builtin_amdgcn_mfma_f32_16x16x32_f16(a0, b0, acc00, 0, 0, 0);
      acc01 = __builtin_amdgcn_mfma_f32_16x16x32_f16(a0, b1, acc01, 0, 0, 0);
      acc10 = __builtin_amdgcn_mfma_f32_16x16x32_f16(a1, b0, acc10, 0, 0, 0);
      acc11 = __builtin_amdgcn_mfma_f32_16x16x32_f16(a1, b1, acc11, 0, 0, 0);
    }
    if (c + 1 < NCH) {                     // cvt + LDS write after MFMA
      int nb = cur ^ 1;
      *(uint4*)&Ab[nb][aoff] = cvt8n(fAa, fAb);
      *(uint4*)&Bb[nb][boff0] = sB0;
      *(uint4*)&Bb[nb][boff1] = sB1;
      *(uint4*)&Bb[nb][boff2] = sB2;
      *(uint4*)&Bb[nb][boff3] = sB3;
    }
    __syncthreads();
  }

  float v0[4], v1[4];
#pragma unroll
  for (int j = 0; j < 4; j++) {
    v0[j] = fminf(p2v0 - 2.f * acc00[j], p2v1 - 2.f * acc01[j]);
    v1[j] = fminf(p2v0 - 2.f * acc10[j], p2v1 - 2.f * acc11[j]);
  }
#pragma unroll
  for (int mask = 1; mask < 16; mask <<= 1) {
#pragma unroll
    for (int j = 0; j < 4; j++) {
      v0[j] = fminf(v0[j], __shfl_xor(v0[j], mask));
      v1[j] = fminf(v1[j], __shfl_xor(v1[j], mask));
    }
  }
  if (lc == 0) {
#pragma unroll
    for (int j = 0; j < 4; j++) {
      red[lk * 4 + j][w] = v0[j];
      red[16 + lk * 4 + j][w] = v1[j];
    }
  }
  __syncthreads();
  if (t < 64) {
    float val = 0.f;
    if (t < nf) {
      float m = fminf(fminf(red[t][0], red[t][1]), fminf(red[t][2], red[t][3]));
      float d2 = f2[glist[t]] + m;
      val = sqrtf(fmaxf(d2, 0.f)) * (1.0f / (float)N_FEAT);
    }
    val = wave_reduce_sum(val);
    if (t == 0) atomicAdd(out, val);
  }
}

extern "C" void kernel_launch(void* const* d_in, const int* in_sizes, int n_in,
                              void* d_out, int out_size, void* d_ws, size_t ws_size,
                              hipStream_t stream) {
  (void)in_sizes; (void)n_in; (void)out_size; (void)ws_size;
  const float* feat   = (const float*)d_in[0];
  const float* coarse = (const float*)d_in[1];
  const float* fine   = (const float*)d_in[2];
  float* out = (float*)d_out;

  ush* fine_h    = (ush*)d_ws;                           // 8192*512 fp16
  float* f2      = (float*)(fine_h + (size_t)KC * MF * DIM);  // 8192
  float* p2      = f2 + N_FEAT;             // 8192
  int* assign    = (int*)(p2 + KC * MF);    // 8192
  int* hist_part = assign + N_FEAT;         // 128*64

  k1_assign_cvt_kernel<<<384, 256, 0, stream>>>(
      feat, coarse, fine, fine_h, f2, p2, assign, hist_part, out);
  fine_mfma_kernel<<<MAXTILES, 256, 0, stream>>>(feat, fine_h, f2, p2, assign,
                                                 hist_part, out);
}